// Round 4
// baseline (175.428 us; speedup 1.0000x reference)
//
#include <hip/hip_runtime.h>

#define NTOK 256
#define DIM  128
#define HD   32
#define NWIN 64

typedef __bf16 bf16x8 __attribute__((ext_vector_type(8)));
typedef __bf16 bf16x4 __attribute__((ext_vector_type(4)));
typedef float  f32x4  __attribute__((ext_vector_type(4)));

__device__ __forceinline__ float bf2f(unsigned short s) {
    union { unsigned u; float f; } x; x.u = ((unsigned)s) << 16; return x.f;
}

// ---- LDS layout (bytes) ----
// x:   [256][128] bf16, 256B rows, XOR swizzle bits4-6   -> 65536
// W:   [96][128]  bf16, 256B rows, same swizzle          -> 24576
// Q,K: [256][32]  bf16, 64B rows,  XOR swizzle bits4-5   -> 16384 each
// Vt:  [32][256]  bf16, 512B rows, XOR swizzle bits4-6   -> 16384
// P-staging: per-wave 2KB, overlaps x region after barrier
#define X_OFF 0
#define W_OFF 65536
#define Q_OFF 90112
#define K_OFF 106496
#define V_OFF 122880
#define LDS_BYTES 139264

__device__ __forceinline__ int swz256(int row, int b) { return row * 256 + (b ^ ((row & 7) << 4)); }
__device__ __forceinline__ int swz64 (int row, int b) { return row * 64  + (b ^ (((row >> 1) & 3) << 4)); }
__device__ __forceinline__ int swzV  (int d,   int b) { return d   * 512 + (b ^ ((d & 7) << 4)); }

__device__ __forceinline__ unsigned f2bf_rne(float f) {
    union { float f; unsigned u; } x; x.f = f;
    return (x.u + 0x7FFF + ((x.u >> 16) & 1)) >> 16;
}

// relative-position table index for token pair (i, j)
__device__ __forceinline__ int rel_idx(int i, int j) {
    int di = i >> 6, hi = (i >> 3) & 7, wi = i & 7;
    int dj = j >> 6, hj = (j >> 3) & 7, wj = j & 7;
    return 225 * (di - dj + 3) + 15 * (hi - hj + 7) + (wi - wj + 7);
}

// ---------------- kernel 1a: comb[w][h][i][j] = mask[w][i][j] + rel_bias[h][i][j] (bf16) ----------------
__global__ void comb_kernel(const float* __restrict__ mask, const float* __restrict__ table,
                            unsigned short* __restrict__ comb) {
    int gid = blockIdx.x * 256 + threadIdx.x;                 // 64*4*256*256 = 16,777,216
    int j = gid & 255, i = (gid >> 8) & 255, h = (gid >> 16) & 3, w = gid >> 18;
    float v = mask[(w << 16) | (i << 8) | j] + table[rel_idx(i, j) * 4 + h];
    comb[gid] = (unsigned short)f2bf_rne(v);
}

// ---------------- kernel 1b: bias[h][i][j] = rel_bias_table[rel_idx(i,j)][h] (bf16, 512KB) ----------------
__global__ void bias_kernel(const float* __restrict__ table, unsigned short* __restrict__ bias) {
    int gid = blockIdx.x * 256 + threadIdx.x;                 // 4*256*256 = 262,144
    int j = gid & 255, i = (gid >> 8) & 255, h = gid >> 16;
    bias[gid] = (unsigned short)f2bf_rne(table[rel_idx(i, j) * 4 + h]);
}

// ---------------- kernel 2: fused QKV projection + windowed attention ----------------
// MODE 0: aux16 = comb[w][h][i][j] bf16 (mask+bias pre-added)
// MODE 1: aux16 = bias[h][i][j] bf16; mask read fp32
// MODE 2: no workspace; table gather + mask fp32 inline
template <int MODE>
__global__ __launch_bounds__(512, 2) void attn_kernel(
    const float* __restrict__ x, const float* __restrict__ qkv_w,
    const float* __restrict__ q_bias, const float* __restrict__ v_bias,
    const unsigned short* __restrict__ aux16, const float* __restrict__ mask,
    const float* __restrict__ table, float* __restrict__ out) {
    extern __shared__ char smem[];
    const int tid = threadIdx.x;
    const int bb = blockIdx.x >> 2, h = blockIdx.x & 3;
    const int w = tid >> 6, lane = tid & 63, lr = lane & 15, lg = lane >> 4;

    // ---- stage x[bb] -> bf16 LDS ----
    const float* xp = x + (size_t)bb * (NTOK * DIM);
    #pragma unroll
    for (int it = 0; it < 8; ++it) {
        int base = (it * 512 + tid) * 8;                      // 4096 chunks of 8 floats
        int row = base >> 7, col = base & 127;
        float4 f0 = *(const float4*)(xp + base);
        float4 f1 = *(const float4*)(xp + base + 4);
        union { bf16x8 v; __bf16 e[8]; } u8;
        u8.e[0] = (__bf16)f0.x; u8.e[1] = (__bf16)f0.y; u8.e[2] = (__bf16)f0.z; u8.e[3] = (__bf16)f0.w;
        u8.e[4] = (__bf16)f1.x; u8.e[5] = (__bf16)f1.y; u8.e[6] = (__bf16)f1.z; u8.e[7] = (__bf16)f1.w;
        *(bf16x8*)(smem + X_OFF + swz256(row, col * 2)) = u8.v;
    }
    // ---- stage this head's W rows: [0..32)=Q, [32..64)=K, [64..96)=V ----
    #pragma unroll
    for (int it = 0; it < 3; ++it) {
        int base = (it * 512 + tid) * 8;                      // 1536 chunks
        int row = base >> 7, col = base & 127;
        int sec = row >> 5, r5 = row & 31;
        const float* wp = qkv_w + ((sec * 128 + h * 32 + r5) * DIM + col);
        float4 f0 = *(const float4*)(wp);
        float4 f1 = *(const float4*)(wp + 4);
        union { bf16x8 v; __bf16 e[8]; } u8;
        u8.e[0] = (__bf16)f0.x; u8.e[1] = (__bf16)f0.y; u8.e[2] = (__bf16)f0.z; u8.e[3] = (__bf16)f0.w;
        u8.e[4] = (__bf16)f1.x; u8.e[5] = (__bf16)f1.y; u8.e[6] = (__bf16)f1.z; u8.e[7] = (__bf16)f1.w;
        *(bf16x8*)(smem + W_OFF + swz256(row, col * 2)) = u8.v;
    }
    __syncthreads();

    // ---- projection: each wave computes its 32 token-rows for all 6 n-tiles ----
    const float SCALE = 0.17677669529663687f;                 // 1/sqrt(32)
    #pragma unroll
    for (int mi = 0; mi < 2; ++mi) {
        int mt = w * 2 + mi;
        bf16x8 xa[4];
        #pragma unroll
        for (int kk = 0; kk < 4; ++kk)
            xa[kk] = *(bf16x8*)(smem + X_OFF + swz256(mt * 16 + lr, kk * 64 + lg * 16));
        #pragma unroll
        for (int nt = 0; nt < 6; ++nt) {
            f32x4 acc = {0.f, 0.f, 0.f, 0.f};
            #pragma unroll
            for (int kk = 0; kk < 4; ++kk) {
                bf16x8 wb = *(bf16x8*)(smem + W_OFF + swz256(nt * 16 + lr, kk * 64 + lg * 16));
                acc = __builtin_amdgcn_mfma_f32_16x16x32_bf16(xa[kk], wb, acc, 0, 0, 0);
            }
            int sec = nt >> 1;                                // 0=Q 1=K 2=V
            int d = (nt & 1) * 16 + lr;
            float bias = 0.f;
            if (sec == 0) bias = q_bias[h * 32 + d];
            if (sec == 2) bias = v_bias[h * 32 + d];
            #pragma unroll
            for (int r = 0; r < 4; ++r) {
                int row = mt * 16 + lg * 4 + r;               // verified C layout
                float val = acc[r] + bias;
                if (sec == 0) {
                    val *= SCALE;
                    *(__bf16*)(smem + Q_OFF + swz64(row, d * 2)) = (__bf16)val;
                } else if (sec == 1) {
                    *(__bf16*)(smem + K_OFF + swz64(row, d * 2)) = (__bf16)val;
                } else {
                    *(__bf16*)(smem + V_OFF + swzV(d, row * 2)) = (__bf16)val;   // V transposed
                }
            }
        }
    }
    __syncthreads();

    // ---- attention: wave owns Q rows [w*32, w*32+32) ----
    bf16x8 qf[2];
    #pragma unroll
    for (int tt = 0; tt < 2; ++tt)
        qf[tt] = *(bf16x8*)(smem + Q_OFF + swz64(w * 32 + tt * 16 + lr, lg * 16));

    // S^T = K * Q^T  (lane holds S[q=lr][j = kt*16 + lg*4 + reg])
    f32x4 st[2][16];
    #pragma unroll
    for (int kt = 0; kt < 16; ++kt) {
        bf16x8 kf = *(bf16x8*)(smem + K_OFF + swz64(kt * 16 + lr, lg * 16));
        f32x4 z = {0.f, 0.f, 0.f, 0.f};
        st[0][kt] = __builtin_amdgcn_mfma_f32_16x16x32_bf16(kf, qf[0], z, 0, 0, 0);
        st[1][kt] = __builtin_amdgcn_mfma_f32_16x16x32_bf16(kf, qf[1], z, 0, 0, 0);
    }

    // ---- + (mask + rel_bias), row softmax ----
    const int w_idx = bb & 63;
    float inv[2];
    #pragma unroll
    for (int tt = 0; tt < 2; ++tt) {
        int rg = w * 32 + tt * 16 + lr;
        float mx = -3.0e38f;
        #pragma unroll
        for (int kt = 0; kt < 16; ++kt) {
            if (MODE == 0) {
                const unsigned short* crow =
                    aux16 + (((size_t)(w_idx * 4 + h)) << 16) + rg * 256 + lg * 4;
                ushort4 c4 = *(const ushort4*)(crow + kt * 16);
                st[tt][kt][0] += bf2f(c4.x);
                st[tt][kt][1] += bf2f(c4.y);
                st[tt][kt][2] += bf2f(c4.z);
                st[tt][kt][3] += bf2f(c4.w);
            } else if (MODE == 1) {
                const unsigned short* brow = aux16 + (((size_t)h) << 16) + rg * 256 + lg * 4;
                const float* mrow = mask + (((size_t)w_idx) << 16) + rg * 256 + lg * 4;
                ushort4 c4 = *(const ushort4*)(brow + kt * 16);
                float4 m4 = *(const float4*)(mrow + kt * 16);
                st[tt][kt][0] += bf2f(c4.x) + m4.x;
                st[tt][kt][1] += bf2f(c4.y) + m4.y;
                st[tt][kt][2] += bf2f(c4.z) + m4.z;
                st[tt][kt][3] += bf2f(c4.w) + m4.w;
            } else {
                const float* mrow = mask + (((size_t)w_idx) << 16) + rg * 256 + lg * 4;
                float4 m4 = *(const float4*)(mrow + kt * 16);
                #pragma unroll
                for (int c = 0; c < 4; ++c) {
                    int j = kt * 16 + lg * 4 + c;
                    float m = (c == 0) ? m4.x : (c == 1) ? m4.y : (c == 2) ? m4.z : m4.w;
                    st[tt][kt][c] += table[rel_idx(rg, j) * 4 + h] + m;
                }
            }
            mx = fmaxf(mx, fmaxf(fmaxf(st[tt][kt][0], st[tt][kt][1]),
                                 fmaxf(st[tt][kt][2], st[tt][kt][3])));
        }
        mx = fmaxf(mx, __shfl_xor(mx, 16));
        mx = fmaxf(mx, __shfl_xor(mx, 32));
        float sum = 0.f;
        #pragma unroll
        for (int kt = 0; kt < 16; ++kt) {
            #pragma unroll
            for (int c = 0; c < 4; ++c) {
                float e = __expf(st[tt][kt][c] - mx);
                st[tt][kt][c] = e;
                sum += e;
            }
        }
        sum += __shfl_xor(sum, 16);
        sum += __shfl_xor(sum, 32);
        inv[tt] = 1.0f / sum;
    }

    // ---- PV: stage P chunk (32 j) per wave in LDS (x region reuse), MFMA with Vt ----
    char* pbuf = smem + X_OFF + w * 2048;
    f32x4 oacc[2][2];
    #pragma unroll
    for (int tt = 0; tt < 2; ++tt)
        #pragma unroll
        for (int u = 0; u < 2; ++u)
            oacc[tt][u] = (f32x4){0.f, 0.f, 0.f, 0.f};

    #pragma unroll
    for (int s = 0; s < 8; ++s) {
        #pragma unroll
        for (int tt = 0; tt < 2; ++tt) {
            #pragma unroll
            for (int half = 0; half < 2; ++half) {
                f32x4 p = st[tt][2 * s + half];
                union { bf16x4 v; __bf16 e[4]; } u4;
                u4.e[0] = (__bf16)(p[0] * inv[tt]);
                u4.e[1] = (__bf16)(p[1] * inv[tt]);
                u4.e[2] = (__bf16)(p[2] * inv[tt]);
                u4.e[3] = (__bf16)(p[3] * inv[tt]);
                *(bf16x4*)(pbuf + swz64(tt * 16 + lr, half * 32 + lg * 8)) = u4.v;
            }
        }
        bf16x8 vf[2];
        #pragma unroll
        for (int u = 0; u < 2; ++u)
            vf[u] = *(bf16x8*)(smem + V_OFF + swzV(u * 16 + lr, s * 64 + lg * 16));
        #pragma unroll
        for (int tt = 0; tt < 2; ++tt) {
            bf16x8 af = *(bf16x8*)(pbuf + swz64(tt * 16 + lr, lg * 16));
            #pragma unroll
            for (int u = 0; u < 2; ++u)
                oacc[tt][u] = __builtin_amdgcn_mfma_f32_16x16x32_bf16(af, vf[u], oacc[tt][u], 0, 0, 0);
        }
    }

    // ---- write out[bb][n][h*32+d] ----
    float* op = out + (((size_t)bb * 256 + w * 32) * 128) + h * 32;
    #pragma unroll
    for (int tt = 0; tt < 2; ++tt)
        #pragma unroll
        for (int u = 0; u < 2; ++u)
            #pragma unroll
            for (int r = 0; r < 4; ++r)
                op[(tt * 16 + lg * 4 + r) * 128 + u * 16 + lr] = oacc[tt][u][r];
}

extern "C" void kernel_launch(void* const* d_in, const int* in_sizes, int n_in,
                              void* d_out, int out_size, void* d_ws, size_t ws_size,
                              hipStream_t stream) {
    const float* x      = (const float*)d_in[0];
    const float* mask   = (const float*)d_in[1];
    const float* qkv_w  = (const float*)d_in[2];
    const float* q_bias = (const float*)d_in[3];
    const float* v_bias = (const float*)d_in[4];
    const float* table  = (const float*)d_in[5];
    float* out = (float*)d_out;
    (void)in_sizes; (void)n_in; (void)out_size;

    const size_t NEED_COMB = (size_t)NWIN * 4 * 256 * 256 * 2;  // 32 MB
    const size_t NEED_BIAS = (size_t)4 * 256 * 256 * 2;         // 512 KB

    if (ws_size >= NEED_COMB) {
        unsigned short* comb = (unsigned short*)d_ws;
        comb_kernel<<<65536, 256, 0, stream>>>(mask, table, comb);
        hipFuncSetAttribute((const void*)attn_kernel<0>,
                            hipFuncAttributeMaxDynamicSharedMemorySize, LDS_BYTES);
        attn_kernel<0><<<2048, 512, LDS_BYTES, stream>>>(x, qkv_w, q_bias, v_bias,
                                                         comb, mask, table, out);
    } else if (ws_size >= NEED_BIAS) {
        unsigned short* bias = (unsigned short*)d_ws;
        bias_kernel<<<1024, 256, 0, stream>>>(table, bias);
        hipFuncSetAttribute((const void*)attn_kernel<1>,
                            hipFuncAttributeMaxDynamicSharedMemorySize, LDS_BYTES);
        attn_kernel<1><<<2048, 512, LDS_BYTES, stream>>>(x, qkv_w, q_bias, v_bias,
                                                         bias, mask, table, out);
    } else {
        hipFuncSetAttribute((const void*)attn_kernel<2>,
                            hipFuncAttributeMaxDynamicSharedMemorySize, LDS_BYTES);
        attn_kernel<2><<<2048, 512, LDS_BYTES, stream>>>(x, qkv_w, q_bias, v_bias,
                                                         nullptr, mask, table, out);
    }
}